// Round 1
// baseline (944.685 us; speedup 1.0000x reference)
//
#include <hip/hip_runtime.h>
#include <hip/hip_bf16.h>
#include <math.h>

// B=2, S=2048, D=1024, H=16, hd=64. scaling=0.125, LN eps=1e-5.
typedef __bf16 bf16;
typedef __bf16 bf16x4 __attribute__((ext_vector_type(4)));
typedef __bf16 bf16x8 __attribute__((ext_vector_type(8)));
typedef float floatx4 __attribute__((ext_vector_type(4)));

#define MFMA16(a, b, c) __builtin_amdgcn_mfma_f32_16x16x32_bf16(a, b, c, 0, 0, 0)

// async global->LDS, 16B per lane; lds base must be wave-uniform (lane i lands
// at lds + i*16). [m97: global_load_lds_dwordx4]
__device__ __forceinline__ void gl_lds16(const void* g, void* l) {
  __builtin_amdgcn_global_load_lds(
      (const __attribute__((address_space(1))) void*)(g),
      (__attribute__((address_space(3))) void*)(l), 16, 0, 0);
}

// ---------------- K0: fp32 -> bf16 conversions --------------------------
__global__ __launch_bounds__(256) void k_convert(
    const float* __restrict__ hid, const float* __restrict__ wq,
    const float* __restrict__ wk, const float* __restrict__ wv,
    const float* __restrict__ wo,
    bf16* __restrict__ hidb, bf16* __restrict__ wqkvb, bf16* __restrict__ wob) {
  int g = blockIdx.x * 256 + threadIdx.x;
  int idx = g * 4;
  const float* src;
  bf16* dst;
  if (idx < 4194304) {
    src = hid + idx; dst = hidb + idx;
  } else if (idx < 7340032) {
    const float* w = (idx < 5242880) ? wq : (idx < 6291456) ? wk : wv;
    src = w + ((idx - 4194304) & 1048575);
    dst = wqkvb + (idx - 4194304);
  } else {
    src = wo + (idx - 7340032); dst = wob + (idx - 7340032);
  }
  float4 v = *(const float4*)src;
  bf16x4 o;
  o[0] = (bf16)v.x; o[1] = (bf16)v.y; o[2] = (bf16)v.z; o[3] = (bf16)v.w;
  *(bf16x4*)dst = o;
}

// ---------------- K1: fused QKV GEMM (m97-class staging) ------------------
__global__ __launch_bounds__(256) void k_qkv_gemm(
    const bf16* __restrict__ A, const bf16* __restrict__ Bt,
    const float* __restrict__ bq, const float* __restrict__ bk,
    const float* __restrict__ bv,
    bf16* __restrict__ Qb, bf16* __restrict__ Kb, bf16* __restrict__ Vb) {
  __shared__ __align__(16) bf16 Al[128 * 64];
  __shared__ __align__(16) bf16 Bl[128 * 64];
  int tid = threadIdx.x;
  int wave = tid >> 6, L = tid & 63, quad = L >> 4, ln = L & 15;
  int m0 = blockIdx.y * 128, n0 = blockIdx.x * 128;
  int wm = (wave >> 1) * 64, wn = (wave & 1) * 64;

  floatx4 zz = {0.f, 0.f, 0.f, 0.f};
  floatx4 acc[4][4];
#pragma unroll
  for (int i = 0; i < 4; i++)
#pragma unroll
    for (int j = 0; j < 4; j++) acc[i][j] = zz;

  for (int kk = 0; kk < 1024; kk += 64) {
    __syncthreads();
#pragma unroll
    for (int u = 0; u < 4; u++) {
      int chw = u * 256 + wave * 64;  // wave-uniform chunk base
      int ch = chw + L;
      int r = ch >> 3, c8 = ch & 7;
      gl_lds16(&A[(size_t)(m0 + r) * 1024 + kk + c8 * 8], &Al[chw * 8]);
      gl_lds16(&Bt[(size_t)(n0 + r) * 1024 + kk + c8 * 8], &Bl[chw * 8]);
    }
    __syncthreads();
#pragma unroll
    for (int t = 0; t < 64; t += 32) {
      bf16x8 af[4], bfr[4];
#pragma unroll
      for (int i = 0; i < 4; i++)
        af[i] = *(const bf16x8*)&Al[(wm + i * 16 + ln) * 64 + t + quad * 8];
#pragma unroll
      for (int j = 0; j < 4; j++)
        bfr[j] = *(const bf16x8*)&Bl[(wn + j * 16 + ln) * 64 + t + quad * 8];
#pragma unroll
      for (int i = 0; i < 4; i++)
#pragma unroll
        for (int j = 0; j < 4; j++) acc[i][j] = MFMA16(af[i], bfr[j], acc[i][j]);
    }
  }
#pragma unroll
  for (int i = 0; i < 4; i++) {
    int mbase = m0 + wm + i * 16 + quad * 4;
    int b = mbase >> 11, s0 = mbase & 2047;
#pragma unroll
    for (int j = 0; j < 4; j++) {
      int n = n0 + wn + j * 16 + ln;
      int which = n >> 10, nn = n & 1023;
      float bias = (which == 0) ? bq[nn] : (which == 1) ? bk[nn] : bv[nn];
      int h = nn >> 6, d = nn & 63;
      int bh = b * 16 + h;
      if (which == 2) {
        bf16x4 v4;
#pragma unroll
        for (int r = 0; r < 4; r++) v4[r] = (bf16)(acc[i][j][r] + bias);
        *(bf16x4*)&Vb[(size_t)bh * 131072 + (size_t)d * 2048 + s0] = v4;
      } else {
#pragma unroll
        for (int r = 0; r < 4; r++) {
          float v = acc[i][j][r] + bias;
          if (which == 0)
            Qb[(size_t)bh * 131072 + (s0 + r) * 64 + d] = (bf16)(v * 0.125f);
          else
            Kb[(size_t)bh * 131072 + (s0 + r) * 64 + d] = (bf16)v;
        }
      }
    }
  }
}

// ---------------- K2: flash attention + extra_attn + mask ----------------
// 64 q-rows/block (4 waves x 16), K-tile 64. K,V double-buffered async
// global_load_lds (one tile ahead). extra+mask are FUSED into a single
// register prefetch (one tile ahead) — no LDS staging for extra. The
// per-lane pattern (4 rows x 16 contiguous floats = 64B segments) coalesces
// fine as plain global loads. LDS 40 KB -> 4 blocks/CU (was 72 KB -> 2).
__global__ __launch_bounds__(256, 4) void k_attn(
    const bf16* __restrict__ Qb, const bf16* __restrict__ Kb,
    const bf16* __restrict__ Vb, const float* __restrict__ extra,
    const float* __restrict__ mask, bf16* __restrict__ ctx) {
  __shared__ __align__(16) bf16 Kl[2][64 * 64];    // 16 KB
  __shared__ __align__(16) bf16 Vtl[2][64 * 64];   // 16 KB
  __shared__ __align__(16) bf16 Pl[4][16 * 64];    // 8 KB   -> 40 KB total
  int tid = threadIdx.x;
  int wave = tid >> 6, L = tid & 63, quad = L >> 4, ln = L & 15;
  int bh = blockIdx.y, b = bh >> 4;
  int q0 = blockIdx.x * 64;
  int qrow = q0 + wave * 16;
  int h = bh & 15;

  bf16x8 qf[2];
  qf[0] = *(const bf16x8*)&Qb[(size_t)bh * 131072 + (qrow + ln) * 64 + quad * 8];
  qf[1] = *(const bf16x8*)&Qb[(size_t)bh * 131072 + (qrow + ln) * 64 + 32 + quad * 8];

  float m_run[4], l_run[4];
  floatx4 zz = {0.f, 0.f, 0.f, 0.f};
  floatx4 Oacc[4];
#pragma unroll
  for (int r = 0; r < 4; r++) { m_run[r] = -INFINITY; l_run[r] = 0.f; }
#pragma unroll
  for (int dd = 0; dd < 4; dd++) Oacc[dd] = zz;

  // uniform bases (SGPR) + per-lane 32-bit element offsets: lets the compiler
  // use saddr-form global_load_dword with small imm offsets for kb.
  const float* eb = extra + (size_t)bh * 4194304;
  const float* mb = mask + (size_t)b * 4194304;
  int voff[4];
#pragma unroll
  for (int r = 0; r < 4; r++) voff[r] = (qrow + quad * 4 + r) * 2048 + ln;

  // ---- tile-0 staging: K, V into buf 0 ----
#pragma unroll
  for (int u = 0; u < 2; u++) {
    int chw = u * 256 + wave * 64;
    int ch = chw + L;
    int row = ch >> 3, c8 = ch & 7;
    gl_lds16(&Kb[(size_t)bh * 131072 + row * 64 + c8 * 8], &Kl[0][chw * 8]);
    gl_lds16(&Vb[(size_t)bh * 131072 + (size_t)row * 2048 + c8 * 8], &Vtl[0][chw * 8]);
  }
  // tile-0 extra+mask register prefetch (fused add — one value per (kb,r))
  float emc[4][4];
#pragma unroll
  for (int kb = 0; kb < 4; kb++)
#pragma unroll
    for (int r = 0; r < 4; r++)
      emc[kb][r] = eb[voff[r] + kb * 16] + mb[voff[r] + kb * 16];

  for (int t = 0; t < 32; t++) {
    __syncthreads();  // drains vmcnt: tile-t DMA + em prefetch complete
    if (t < 31) {     // stage tile t+1 (other buffer) — full tile of slack
      int k0n = (t + 1) * 64;
      bf16* Kn = Kl[(t + 1) & 1];
      bf16* Vn = Vtl[(t + 1) & 1];
#pragma unroll
      for (int u = 0; u < 2; u++) {
        int chw = u * 256 + wave * 64;
        int ch = chw + L;
        int row = ch >> 3, c8 = ch & 7;
        gl_lds16(&Kb[(size_t)bh * 131072 + (k0n + row) * 64 + c8 * 8], &Kn[chw * 8]);
        gl_lds16(&Vb[(size_t)bh * 131072 + (size_t)row * 2048 + k0n + c8 * 8], &Vn[chw * 8]);
      }
    }
    // next-tile extra+mask prefetch (consumed next iteration)
    float emn[4][4];
    if (t < 31) {
#pragma unroll
      for (int kb = 0; kb < 4; kb++)
#pragma unroll
        for (int r = 0; r < 4; r++)
          emn[kb][r] = eb[voff[r] + 64 + kb * 16] + mb[voff[r] + 64 + kb * 16];
    }
    const bf16* Kc = Kl[t & 1];
    const bf16* Vc = Vtl[t & 1];

    // scores: 16q x 64k per wave
    floatx4 sc[4];
#pragma unroll
    for (int kb = 0; kb < 4; kb++) {
      bf16x8 kf0 = *(const bf16x8*)&Kc[(kb * 16 + ln) * 64 + quad * 8];
      bf16x8 kf1 = *(const bf16x8*)&Kc[(kb * 16 + ln) * 64 + 32 + quad * 8];
      floatx4 z = zz;
      z = MFMA16(qf[0], kf0, z);
      z = MFMA16(qf[1], kf1, z);
      sc[kb] = z;
    }
    // + (extra + mask), register-prefetched
#pragma unroll
    for (int kb = 0; kb < 4; kb++)
#pragma unroll
      for (int r = 0; r < 4; r++) sc[kb][r] += emc[kb][r];

    // online softmax over the 16-lane k groups
#pragma unroll
    for (int r = 0; r < 4; r++) {
      float mloc = fmaxf(fmaxf(sc[0][r], sc[1][r]), fmaxf(sc[2][r], sc[3][r]));
      mloc = fmaxf(mloc, __shfl_xor(mloc, 1));
      mloc = fmaxf(mloc, __shfl_xor(mloc, 2));
      mloc = fmaxf(mloc, __shfl_xor(mloc, 4));
      mloc = fmaxf(mloc, __shfl_xor(mloc, 8));
      float m_new = fmaxf(m_run[r], mloc);
      float alpha = __expf(m_run[r] - m_new);
      m_run[r] = m_new;
      float rs = 0.f;
#pragma unroll
      for (int kb = 0; kb < 4; kb++) {
        float p = __expf(sc[kb][r] - m_new);
        sc[kb][r] = p;
        rs += p;
      }
      rs += __shfl_xor(rs, 1);
      rs += __shfl_xor(rs, 2);
      rs += __shfl_xor(rs, 4);
      rs += __shfl_xor(rs, 8);
      l_run[r] = l_run[r] * alpha + rs;
#pragma unroll
      for (int dd = 0; dd < 4; dd++) Oacc[dd][r] *= alpha;
#pragma unroll
      for (int kb = 0; kb < 4; kb++)
        Pl[wave][(quad * 4 + r) * 64 + kb * 16 + ln] = (bf16)sc[kb][r];
    }
    // PV
    bf16x8 pf0 = *(const bf16x8*)&Pl[wave][ln * 64 + quad * 8];
    bf16x8 pf1 = *(const bf16x8*)&Pl[wave][ln * 64 + 32 + quad * 8];
#pragma unroll
    for (int dd = 0; dd < 4; dd++) {
      bf16x8 vf0 = *(const bf16x8*)&Vc[(dd * 16 + ln) * 64 + quad * 8];
      bf16x8 vf1 = *(const bf16x8*)&Vc[(dd * 16 + ln) * 64 + 32 + quad * 8];
      Oacc[dd] = MFMA16(pf0, vf0, Oacc[dd]);
      Oacc[dd] = MFMA16(pf1, vf1, Oacc[dd]);
    }
    // rotate em prefetch
    if (t < 31) {
#pragma unroll
      for (int kb = 0; kb < 4; kb++)
#pragma unroll
        for (int r = 0; r < 4; r++) emc[kb][r] = emn[kb][r];
#pragma unroll
      for (int r = 0; r < 4; r++) voff[r] += 64;
    }
  }
  // write context [b, q, h*64+d] bf16
#pragma unroll
  for (int dd = 0; dd < 4; dd++) {
#pragma unroll
    for (int r = 0; r < 4; r++) {
      int q = qrow + quad * 4 + r;
      float v = Oacc[dd][r] / l_run[r];
      ctx[((size_t)(b * 2048 + q)) * 1024 + h * 64 + dd * 16 + ln] = (bf16)v;
    }
  }
}

// ---------------- K3a: output proj + bias + residual ---------------------
__global__ __launch_bounds__(256) void k_out_gemm(
    const bf16* __restrict__ A, const bf16* __restrict__ Bt,
    const float* __restrict__ bo, const float* __restrict__ hid,
    float* __restrict__ y) {
  __shared__ __align__(16) bf16 Al[64 * 64];
  __shared__ __align__(16) bf16 Bl[128 * 64];
  int tid = threadIdx.x;
  int wave = tid >> 6, L = tid & 63, quad = L >> 4, ln = L & 15;
  int m0 = blockIdx.y * 64, n0 = blockIdx.x * 128;
  int wm = (wave >> 1) * 32, wn = (wave & 1) * 64;

  floatx4 zz = {0.f, 0.f, 0.f, 0.f};
  floatx4 acc[2][4];
#pragma unroll
  for (int i = 0; i < 2; i++)
#pragma unroll
    for (int j = 0; j < 4; j++) acc[i][j] = zz;

  for (int kk = 0; kk < 1024; kk += 64) {
    __syncthreads();
#pragma unroll
    for (int u = 0; u < 2; u++) {
      int chw = u * 256 + wave * 64;
      int ch = chw + L;
      int r = ch >> 3, c8 = ch & 7;
      gl_lds16(&A[(size_t)(m0 + r) * 1024 + kk + c8 * 8], &Al[chw * 8]);
    }
#pragma unroll
    for (int u = 0; u < 4; u++) {
      int chw = u * 256 + wave * 64;
      int ch = chw + L;
      int r = ch >> 3, c8 = ch & 7;
      gl_lds16(&Bt[(size_t)(n0 + r) * 1024 + kk + c8 * 8], &Bl[chw * 8]);
    }
    __syncthreads();
#pragma unroll
    for (int t = 0; t < 64; t += 32) {
      bf16x8 af[2], bfr[4];
#pragma unroll
      for (int i = 0; i < 2; i++)
        af[i] = *(const bf16x8*)&Al[(wm + i * 16 + ln) * 64 + t + quad * 8];
#pragma unroll
      for (int j = 0; j < 4; j++)
        bfr[j] = *(const bf16x8*)&Bl[(wn + j * 16 + ln) * 64 + t + quad * 8];
#pragma unroll
      for (int i = 0; i < 2; i++)
#pragma unroll
        for (int j = 0; j < 4; j++) acc[i][j] = MFMA16(af[i], bfr[j], acc[i][j]);
    }
  }
#pragma unroll
  for (int i = 0; i < 2; i++) {
    int mbase = m0 + wm + i * 16 + quad * 4;
#pragma unroll
    for (int j = 0; j < 4; j++) {
      int n = n0 + wn + j * 16 + ln;
      float bias = bo[n];
#pragma unroll
      for (int r = 0; r < 4; r++) {
        int mm = mbase + r;
        y[(size_t)mm * 1024 + n] = acc[i][j][r] + bias + hid[(size_t)mm * 1024 + n];
      }
    }
  }
}

// ---------------- K3b: in-place LayerNorm over rows of 1024 ---------------
__global__ __launch_bounds__(256) void k_ln(float* __restrict__ y,
                                            const float* __restrict__ gamma,
                                            const float* __restrict__ beta) {
  int row = blockIdx.x, tid = threadIdx.x;
  float4 v = *(const float4*)&y[(size_t)row * 1024 + tid * 4];
  float s = v.x + v.y + v.z + v.w;
  float sq = v.x * v.x + v.y * v.y + v.z * v.z + v.w * v.w;
#pragma unroll
  for (int off = 32; off > 0; off >>= 1) {
    s += __shfl_xor(s, off);
    sq += __shfl_xor(sq, off);
  }
  __shared__ float red[8];
  int wave = tid >> 6, L = tid & 63;
  if (L == 0) { red[wave] = s; red[4 + wave] = sq; }
  __syncthreads();
  s = red[0] + red[1] + red[2] + red[3];
  sq = red[4] + red[5] + red[6] + red[7];
  float mu = s * (1.f / 1024.f);
  float var = sq * (1.f / 1024.f) - mu * mu;
  float rstd = rsqrtf(var + 1e-5f);
  float4 g = *(const float4*)&gamma[tid * 4];
  float4 be = *(const float4*)&beta[tid * 4];
  float4 o;
  o.x = (v.x - mu) * rstd * g.x + be.x;
  o.y = (v.y - mu) * rstd * g.y + be.y;
  o.z = (v.z - mu) * rstd * g.z + be.z;
  o.w = (v.w - mu) * rstd * g.w + be.w;
  *(float4*)&y[(size_t)row * 1024 + tid * 4] = o;
}

// ---------------- launch --------------------------------------------------
extern "C" void kernel_launch(void* const* d_in, const int* in_sizes, int n_in,
                              void* d_out, int out_size, void* d_ws,
                              size_t ws_size, hipStream_t stream) {
  const float* hid = (const float*)d_in[0];
  const float* mask = (const float*)d_in[1];
  const float* extra = (const float*)d_in[2];
  const float* Wq = (const float*)d_in[3];
  const float* bq = (const float*)d_in[4];
  const float* Wk = (const float*)d_in[5];
  const float* bk = (const float*)d_in[6];
  const float* Wv = (const float*)d_in[7];
  const float* bv = (const float*)d_in[8];
  const float* Wo = (const float*)d_in[9];
  const float* bo = (const float*)d_in[10];
  const float* gamma = (const float*)d_in[11];
  const float* beta = (const float*)d_in[12];
  float* out = (float*)d_out;

  char* ws = (char*)d_ws;
  bf16* hidb  = (bf16*)(ws);                    //  8 MB [4096,1024]
  bf16* wqkvb = (bf16*)(ws + (8ull << 20));     //  6 MB [3072,1024]
  bf16* wob   = (bf16*)(ws + (14ull << 20));    //  2 MB [1024,1024]
  bf16* Qb    = (bf16*)(ws + (16ull << 20));    //  8 MB [32,2048,64]
  bf16* Kb    = (bf16*)(ws + (24ull << 20));    //  8 MB [32,2048,64]
  bf16* Vb    = (bf16*)(ws + (32ull << 20));    //  8 MB [32,64,2048] (transposed)
  bf16* ctx   = (bf16*)(ws + (40ull << 20));    //  8 MB [4096,1024]

  k_convert<<<8192, 256, 0, stream>>>(hid, Wq, Wk, Wv, Wo, hidb, wqkvb, wob);
  k_qkv_gemm<<<dim3(24, 32), 256, 0, stream>>>(hidb, wqkvb, bq, bk, bv, Qb, Kb, Vb);
  k_attn<<<dim3(32, 32), 256, 0, stream>>>(Qb, Kb, Vb, extra, mask, ctx);
  k_out_gemm<<<dim3(8, 64), 256, 0, stream>>>(ctx, wob, bo, hid, out);
  k_ln<<<4096, 256, 0, stream>>>(out, gamma, beta);
}

// Round 2
// 926.887 us; speedup vs baseline: 1.0192x; 1.0192x over previous
//
#include <hip/hip_runtime.h>
#include <hip/hip_bf16.h>
#include <math.h>

// B=2, S=2048, D=1024, H=16, hd=64. scaling=0.125, LN eps=1e-5.
typedef __bf16 bf16;
typedef __bf16 bf16x4 __attribute__((ext_vector_type(4)));
typedef __bf16 bf16x8 __attribute__((ext_vector_type(8)));
typedef float floatx4 __attribute__((ext_vector_type(4)));

#define MFMA16(a, b, c) __builtin_amdgcn_mfma_f32_16x16x32_bf16(a, b, c, 0, 0, 0)

// async global->LDS, 16B per lane; lds base must be wave-uniform (lane i lands
// at lds + i*16). [m97: global_load_lds_dwordx4]
__device__ __forceinline__ void gl_lds16(const void* g, void* l) {
  __builtin_amdgcn_global_load_lds(
      (const __attribute__((address_space(1))) void*)(g),
      (__attribute__((address_space(3))) void*)(l), 16, 0, 0);
}

// ---------------- K0: fp32 -> bf16 conversions --------------------------
__global__ __launch_bounds__(256) void k_convert(
    const float* __restrict__ hid, const float* __restrict__ wq,
    const float* __restrict__ wk, const float* __restrict__ wv,
    const float* __restrict__ wo,
    bf16* __restrict__ hidb, bf16* __restrict__ wqkvb, bf16* __restrict__ wob) {
  int g = blockIdx.x * 256 + threadIdx.x;
  int idx = g * 4;
  const float* src;
  bf16* dst;
  if (idx < 4194304) {
    src = hid + idx; dst = hidb + idx;
  } else if (idx < 7340032) {
    const float* w = (idx < 5242880) ? wq : (idx < 6291456) ? wk : wv;
    src = w + ((idx - 4194304) & 1048575);
    dst = wqkvb + (idx - 4194304);
  } else {
    src = wo + (idx - 7340032); dst = wob + (idx - 7340032);
  }
  float4 v = *(const float4*)src;
  bf16x4 o;
  o[0] = (bf16)v.x; o[1] = (bf16)v.y; o[2] = (bf16)v.z; o[3] = (bf16)v.w;
  *(bf16x4*)dst = o;
}

// ---------------- K1: fused QKV GEMM (m97-class staging) ------------------
__global__ __launch_bounds__(256) void k_qkv_gemm(
    const bf16* __restrict__ A, const bf16* __restrict__ Bt,
    const float* __restrict__ bq, const float* __restrict__ bk,
    const float* __restrict__ bv,
    bf16* __restrict__ Qb, bf16* __restrict__ Kb, bf16* __restrict__ Vb) {
  __shared__ __align__(16) bf16 Al[128 * 64];
  __shared__ __align__(16) bf16 Bl[128 * 64];
  int tid = threadIdx.x;
  int wave = tid >> 6, L = tid & 63, quad = L >> 4, ln = L & 15;
  int m0 = blockIdx.y * 128, n0 = blockIdx.x * 128;
  int wm = (wave >> 1) * 64, wn = (wave & 1) * 64;

  floatx4 zz = {0.f, 0.f, 0.f, 0.f};
  floatx4 acc[4][4];
#pragma unroll
  for (int i = 0; i < 4; i++)
#pragma unroll
    for (int j = 0; j < 4; j++) acc[i][j] = zz;

  for (int kk = 0; kk < 1024; kk += 64) {
    __syncthreads();
#pragma unroll
    for (int u = 0; u < 4; u++) {
      int chw = u * 256 + wave * 64;  // wave-uniform chunk base
      int ch = chw + L;
      int r = ch >> 3, c8 = ch & 7;
      gl_lds16(&A[(size_t)(m0 + r) * 1024 + kk + c8 * 8], &Al[chw * 8]);
      gl_lds16(&Bt[(size_t)(n0 + r) * 1024 + kk + c8 * 8], &Bl[chw * 8]);
    }
    __syncthreads();
#pragma unroll
    for (int t = 0; t < 64; t += 32) {
      bf16x8 af[4], bfr[4];
#pragma unroll
      for (int i = 0; i < 4; i++)
        af[i] = *(const bf16x8*)&Al[(wm + i * 16 + ln) * 64 + t + quad * 8];
#pragma unroll
      for (int j = 0; j < 4; j++)
        bfr[j] = *(const bf16x8*)&Bl[(wn + j * 16 + ln) * 64 + t + quad * 8];
#pragma unroll
      for (int i = 0; i < 4; i++)
#pragma unroll
        for (int j = 0; j < 4; j++) acc[i][j] = MFMA16(af[i], bfr[j], acc[i][j]);
    }
  }
#pragma unroll
  for (int i = 0; i < 4; i++) {
    int mbase = m0 + wm + i * 16 + quad * 4;
    int b = mbase >> 11, s0 = mbase & 2047;
#pragma unroll
    for (int j = 0; j < 4; j++) {
      int n = n0 + wn + j * 16 + ln;
      int which = n >> 10, nn = n & 1023;
      float bias = (which == 0) ? bq[nn] : (which == 1) ? bk[nn] : bv[nn];
      int h = nn >> 6, d = nn & 63;
      int bh = b * 16 + h;
      if (which == 2) {
        bf16x4 v4;
#pragma unroll
        for (int r = 0; r < 4; r++) v4[r] = (bf16)(acc[i][j][r] + bias);
        *(bf16x4*)&Vb[(size_t)bh * 131072 + (size_t)d * 2048 + s0] = v4;
      } else {
#pragma unroll
        for (int r = 0; r < 4; r++) {
          float v = acc[i][j][r] + bias;
          if (which == 0)
            Qb[(size_t)bh * 131072 + (s0 + r) * 64 + d] = (bf16)(v * 0.125f);
          else
            Kb[(size_t)bh * 131072 + (s0 + r) * 64 + d] = (bf16)v;
        }
      }
    }
  }
}

// ---------------- K2: flash attention + extra_attn + mask ----------------
// 64 q-rows/block (4 waves x 16), K-tile 64. K,V double-buffered async
// global_load_lds; extra+mask fused into a register prefetch.
// NEW: all LDS tiles (K, V, P) are XOR-swizzled to kill the 16-way bank
// conflict of 128B-row-stride ds_read_b128 (G4 / m136 / rule 21):
//  - K,V (global_load_lds, linear dest): pre-swizzle the GLOBAL source
//    chunk  c8 -> c8 ^ (row&7); read chunk quad -> quad ^ (row&7).
//  - P (regular ds ops): XOR element offset with (row&7)<<3 on BOTH sides.
__global__ __launch_bounds__(256, 4) void k_attn(
    const bf16* __restrict__ Qb, const bf16* __restrict__ Kb,
    const bf16* __restrict__ Vb, const float* __restrict__ extra,
    const float* __restrict__ mask, bf16* __restrict__ ctx) {
  __shared__ __align__(16) bf16 Kl[2][64 * 64];    // 16 KB
  __shared__ __align__(16) bf16 Vtl[2][64 * 64];   // 16 KB
  __shared__ __align__(16) bf16 Pl[4][16 * 64];    // 8 KB   -> 40 KB total
  int tid = threadIdx.x;
  int wave = tid >> 6, L = tid & 63, quad = L >> 4, ln = L & 15;
  int bh = blockIdx.y, b = bh >> 4;
  int q0 = blockIdx.x * 64;
  int qrow = q0 + wave * 16;
  int h = bh & 15;

  bf16x8 qf[2];
  qf[0] = *(const bf16x8*)&Qb[(size_t)bh * 131072 + (qrow + ln) * 64 + quad * 8];
  qf[1] = *(const bf16x8*)&Qb[(size_t)bh * 131072 + (qrow + ln) * 64 + 32 + quad * 8];

  float m_run[4], l_run[4];
  floatx4 zz = {0.f, 0.f, 0.f, 0.f};
  floatx4 Oacc[4];
#pragma unroll
  for (int r = 0; r < 4; r++) { m_run[r] = -INFINITY; l_run[r] = 0.f; }
#pragma unroll
  for (int dd = 0; dd < 4; dd++) Oacc[dd] = zz;

  // uniform bases (SGPR) + per-lane 32-bit element offsets.
  const float* eb = extra + (size_t)bh * 4194304;
  const float* mb = mask + (size_t)b * 4194304;
  int voff[4];
#pragma unroll
  for (int r = 0; r < 4; r++) voff[r] = (qrow + quad * 4 + r) * 2048 + ln;

  // ---- tile-0 staging: K, V into buf 0 (source pre-swizzled) ----
#pragma unroll
  for (int u = 0; u < 2; u++) {
    int chw = u * 256 + wave * 64;
    int ch = chw + L;
    int row = ch >> 3, c8 = (ch & 7) ^ (row & 7);
    gl_lds16(&Kb[(size_t)bh * 131072 + row * 64 + c8 * 8], &Kl[0][chw * 8]);
    gl_lds16(&Vb[(size_t)bh * 131072 + (size_t)row * 2048 + c8 * 8], &Vtl[0][chw * 8]);
  }
  // tile-0 extra+mask register prefetch (fused add — one value per (kb,r))
  float emc[4][4];
#pragma unroll
  for (int kb = 0; kb < 4; kb++)
#pragma unroll
    for (int r = 0; r < 4; r++)
      emc[kb][r] = eb[voff[r] + kb * 16] + mb[voff[r] + kb * 16];

  for (int t = 0; t < 32; t++) {
    __syncthreads();  // drains vmcnt: tile-t DMA + em prefetch complete
    if (t < 31) {     // stage tile t+1 (other buffer) — full tile of slack
      int k0n = (t + 1) * 64;
      bf16* Kn = Kl[(t + 1) & 1];
      bf16* Vn = Vtl[(t + 1) & 1];
#pragma unroll
      for (int u = 0; u < 2; u++) {
        int chw = u * 256 + wave * 64;
        int ch = chw + L;
        int row = ch >> 3, c8 = (ch & 7) ^ (row & 7);
        gl_lds16(&Kb[(size_t)bh * 131072 + (k0n + row) * 64 + c8 * 8], &Kn[chw * 8]);
        gl_lds16(&Vb[(size_t)bh * 131072 + (size_t)row * 2048 + k0n + c8 * 8], &Vn[chw * 8]);
      }
    }
    // next-tile extra+mask prefetch (consumed next iteration)
    float emn[4][4];
    if (t < 31) {
#pragma unroll
      for (int kb = 0; kb < 4; kb++)
#pragma unroll
        for (int r = 0; r < 4; r++)
          emn[kb][r] = eb[voff[r] + 64 + kb * 16] + mb[voff[r] + 64 + kb * 16];
    }
    const bf16* Kc = Kl[t & 1];
    const bf16* Vc = Vtl[t & 1];

    // scores: 16q x 64k per wave (swizzled K reads — conflict-free)
    floatx4 sc[4];
#pragma unroll
    for (int kb = 0; kb < 4; kb++) {
      int krow = kb * 16 + ln, sw = krow & 7;
      bf16x8 kf0 = *(const bf16x8*)&Kc[krow * 64 + ((quad ^ sw) * 8)];
      bf16x8 kf1 = *(const bf16x8*)&Kc[krow * 64 + (((quad + 4) ^ sw) * 8)];
      floatx4 z = zz;
      z = MFMA16(qf[0], kf0, z);
      z = MFMA16(qf[1], kf1, z);
      sc[kb] = z;
    }
    // + (extra + mask), register-prefetched
#pragma unroll
    for (int kb = 0; kb < 4; kb++)
#pragma unroll
      for (int r = 0; r < 4; r++) sc[kb][r] += emc[kb][r];

    // online softmax over the 16-lane k groups
#pragma unroll
    for (int r = 0; r < 4; r++) {
      float mloc = fmaxf(fmaxf(sc[0][r], sc[1][r]), fmaxf(sc[2][r], sc[3][r]));
      mloc = fmaxf(mloc, __shfl_xor(mloc, 1));
      mloc = fmaxf(mloc, __shfl_xor(mloc, 2));
      mloc = fmaxf(mloc, __shfl_xor(mloc, 4));
      mloc = fmaxf(mloc, __shfl_xor(mloc, 8));
      float m_new = fmaxf(m_run[r], mloc);
      float alpha = __expf(m_run[r] - m_new);
      m_run[r] = m_new;
      float rs = 0.f;
#pragma unroll
      for (int kb = 0; kb < 4; kb++) {
        float p = __expf(sc[kb][r] - m_new);
        sc[kb][r] = p;
        rs += p;
      }
      rs += __shfl_xor(rs, 1);
      rs += __shfl_xor(rs, 2);
      rs += __shfl_xor(rs, 4);
      rs += __shfl_xor(rs, 8);
      l_run[r] = l_run[r] * alpha + rs;
#pragma unroll
      for (int dd = 0; dd < 4; dd++) Oacc[dd][r] *= alpha;
      int prow = quad * 4 + r, psw = (prow & 7) << 3;
#pragma unroll
      for (int kb = 0; kb < 4; kb++)
        Pl[wave][prow * 64 + ((kb * 16 + ln) ^ psw)] = (bf16)sc[kb][r];
    }
    // PV (swizzled P + V reads — conflict-free)
    int psw = ln & 7;
    bf16x8 pf0 = *(const bf16x8*)&Pl[wave][ln * 64 + ((quad ^ psw) * 8)];
    bf16x8 pf1 = *(const bf16x8*)&Pl[wave][ln * 64 + (((quad + 4) ^ psw) * 8)];
#pragma unroll
    for (int dd = 0; dd < 4; dd++) {
      int vrow = dd * 16 + ln, sw = vrow & 7;
      bf16x8 vf0 = *(const bf16x8*)&Vc[vrow * 64 + ((quad ^ sw) * 8)];
      bf16x8 vf1 = *(const bf16x8*)&Vc[vrow * 64 + (((quad + 4) ^ sw) * 8)];
      Oacc[dd] = MFMA16(pf0, vf0, Oacc[dd]);
      Oacc[dd] = MFMA16(pf1, vf1, Oacc[dd]);
    }
    // rotate em prefetch
    if (t < 31) {
#pragma unroll
      for (int kb = 0; kb < 4; kb++)
#pragma unroll
        for (int r = 0; r < 4; r++) emc[kb][r] = emn[kb][r];
#pragma unroll
      for (int r = 0; r < 4; r++) voff[r] += 64;
    }
  }
  // write context [b, q, h*64+d] bf16
#pragma unroll
  for (int dd = 0; dd < 4; dd++) {
#pragma unroll
    for (int r = 0; r < 4; r++) {
      int q = qrow + quad * 4 + r;
      float v = Oacc[dd][r] / l_run[r];
      ctx[((size_t)(b * 2048 + q)) * 1024 + h * 64 + dd * 16 + ln] = (bf16)v;
    }
  }
}

// ---------------- K3a: output proj + bias + residual ---------------------
__global__ __launch_bounds__(256) void k_out_gemm(
    const bf16* __restrict__ A, const bf16* __restrict__ Bt,
    const float* __restrict__ bo, const float* __restrict__ hid,
    float* __restrict__ y) {
  __shared__ __align__(16) bf16 Al[64 * 64];
  __shared__ __align__(16) bf16 Bl[128 * 64];
  int tid = threadIdx.x;
  int wave = tid >> 6, L = tid & 63, quad = L >> 4, ln = L & 15;
  int m0 = blockIdx.y * 64, n0 = blockIdx.x * 128;
  int wm = (wave >> 1) * 32, wn = (wave & 1) * 64;

  floatx4 zz = {0.f, 0.f, 0.f, 0.f};
  floatx4 acc[2][4];
#pragma unroll
  for (int i = 0; i < 2; i++)
#pragma unroll
    for (int j = 0; j < 4; j++) acc[i][j] = zz;

  for (int kk = 0; kk < 1024; kk += 64) {
    __syncthreads();
#pragma unroll
    for (int u = 0; u < 2; u++) {
      int chw = u * 256 + wave * 64;
      int ch = chw + L;
      int r = ch >> 3, c8 = ch & 7;
      gl_lds16(&A[(size_t)(m0 + r) * 1024 + kk + c8 * 8], &Al[chw * 8]);
    }
#pragma unroll
    for (int u = 0; u < 4; u++) {
      int chw = u * 256 + wave * 64;
      int ch = chw + L;
      int r = ch >> 3, c8 = ch & 7;
      gl_lds16(&Bt[(size_t)(n0 + r) * 1024 + kk + c8 * 8], &Bl[chw * 8]);
    }
    __syncthreads();
#pragma unroll
    for (int t = 0; t < 64; t += 32) {
      bf16x8 af[2], bfr[4];
#pragma unroll
      for (int i = 0; i < 2; i++)
        af[i] = *(const bf16x8*)&Al[(wm + i * 16 + ln) * 64 + t + quad * 8];
#pragma unroll
      for (int j = 0; j < 4; j++)
        bfr[j] = *(const bf16x8*)&Bl[(wn + j * 16 + ln) * 64 + t + quad * 8];
#pragma unroll
      for (int i = 0; i < 2; i++)
#pragma unroll
        for (int j = 0; j < 4; j++) acc[i][j] = MFMA16(af[i], bfr[j], acc[i][j]);
    }
  }
#pragma unroll
  for (int i = 0; i < 2; i++) {
    int mbase = m0 + wm + i * 16 + quad * 4;
#pragma unroll
    for (int j = 0; j < 4; j++) {
      int n = n0 + wn + j * 16 + ln;
      float bias = bo[n];
#pragma unroll
      for (int r = 0; r < 4; r++) {
        int mm = mbase + r;
        y[(size_t)mm * 1024 + n] = acc[i][j][r] + bias + hid[(size_t)mm * 1024 + n];
      }
    }
  }
}

// ---------------- K3b: in-place LayerNorm over rows of 1024 ---------------
__global__ __launch_bounds__(256) void k_ln(float* __restrict__ y,
                                            const float* __restrict__ gamma,
                                            const float* __restrict__ beta) {
  int row = blockIdx.x, tid = threadIdx.x;
  float4 v = *(const float4*)&y[(size_t)row * 1024 + tid * 4];
  float s = v.x + v.y + v.z + v.w;
  float sq = v.x * v.x + v.y * v.y + v.z * v.z + v.w * v.w;
#pragma unroll
  for (int off = 32; off > 0; off >>= 1) {
    s += __shfl_xor(s, off);
    sq += __shfl_xor(sq, off);
  }
  __shared__ float red[8];
  int wave = tid >> 6, L = tid & 63;
  if (L == 0) { red[wave] = s; red[4 + wave] = sq; }
  __syncthreads();
  s = red[0] + red[1] + red[2] + red[3];
  sq = red[4] + red[5] + red[6] + red[7];
  float mu = s * (1.f / 1024.f);
  float var = sq * (1.f / 1024.f) - mu * mu;
  float rstd = rsqrtf(var + 1e-5f);
  float4 g = *(const float4*)&gamma[tid * 4];
  float4 be = *(const float4*)&beta[tid * 4];
  float4 o;
  o.x = (v.x - mu) * rstd * g.x + be.x;
  o.y = (v.y - mu) * rstd * g.y + be.y;
  o.z = (v.z - mu) * rstd * g.z + be.z;
  o.w = (v.w - mu) * rstd * g.w + be.w;
  *(float4*)&y[(size_t)row * 1024 + tid * 4] = o;
}

// ---------------- launch --------------------------------------------------
extern "C" void kernel_launch(void* const* d_in, const int* in_sizes, int n_in,
                              void* d_out, int out_size, void* d_ws,
                              size_t ws_size, hipStream_t stream) {
  const float* hid = (const float*)d_in[0];
  const float* mask = (const float*)d_in[1];
  const float* extra = (const float*)d_in[2];
  const float* Wq = (const float*)d_in[3];
  const float* bq = (const float*)d_in[4];
  const float* Wk = (const float*)d_in[5];
  const float* bk = (const float*)d_in[6];
  const float* Wv = (const float*)d_in[7];
  const float* bv = (const float*)d_in[8];
  const float* Wo = (const float*)d_in[9];
  const float* bo = (const float*)d_in[10];
  const float* gamma = (const float*)d_in[11];
  const float* beta = (const float*)d_in[12];
  float* out = (float*)d_out;

  char* ws = (char*)d_ws;
  bf16* hidb  = (bf16*)(ws);                    //  8 MB [4096,1024]
  bf16* wqkvb = (bf16*)(ws + (8ull << 20));     //  6 MB [3072,1024]
  bf16* wob   = (bf16*)(ws + (14ull << 20));    //  2 MB [1024,1024]
  bf16* Qb    = (bf16*)(ws + (16ull << 20));    //  8 MB [32,2048,64]
  bf16* Kb    = (bf16*)(ws + (24ull << 20));    //  8 MB [32,2048,64]
  bf16* Vb    = (bf16*)(ws + (32ull << 20));    //  8 MB [32,64,2048] (transposed)
  bf16* ctx   = (bf16*)(ws + (40ull << 20));    //  8 MB [4096,1024]

  k_convert<<<8192, 256, 0, stream>>>(hid, Wq, Wk, Wv, Wo, hidb, wqkvb, wob);
  k_qkv_gemm<<<dim3(24, 32), 256, 0, stream>>>(hidb, wqkvb, bq, bk, bv, Qb, Kb, Vb);
  k_attn<<<dim3(32, 32), 256, 0, stream>>>(Qb, Kb, Vb, extra, mask, ctx);
  k_out_gemm<<<dim3(8, 64), 256, 0, stream>>>(ctx, wob, bo, hid, out);
  k_ln<<<4096, 256, 0, stream>>>(out, gamma, beta);
}